// Round 17
// baseline (940.340 us; speedup 1.0000x reference)
//
#include <hip/hip_runtime.h>
#include <math.h>

// LinearBlock: x -> LN1 -> QKV -> linear attention -> Wo+bias+res -> LN2 -> FFN(gelu) -> +res
// B=4, T=8192, D=768, H=12, HD=64, DFF=3072. fp32 in/out; bf16 MFMA internally.
//
// Round-17: R16 (BK=64, 876us) with ONE change: MFMA shape 16x16x32 -> 32x32x16.
// Same frozen 2-barrier compiler-scheduled loop; per K-tile per wave now
// 16 ds_read_b128 + 16 MFMA (vs 32+32) -- shorter critical path between barriers.
// Per-wave 64x64 = 2x2 tiles of 32x32; acc = 4 x f32x16 (64 VGPR, unchanged).
// A/B frag: lane l = row/col l&31, k = (l>>5)*8+j. C/D: col=lane&31,
// row=(reg&3)+8*(reg>>2)+4*(lane>>5)  [guide m74/m101, asymmetric-verified].

#define DEV __device__ __forceinline__

typedef __attribute__((ext_vector_type(8))) short s16x8;    // 8 x bf16 (4 VGPRs)
typedef __attribute__((ext_vector_type(16))) float f32x16;  // 32x32 MFMA accumulator

static constexpr int    Bb   = 4;
static constexpr int    Tt   = 8192;
static constexpr int    Dd   = 768;
static constexpr int    Hh   = 12;
static constexpr size_t Mrows = (size_t)Bb * Tt;           // 32768

DEV float bf2f(unsigned short u) {
    union { unsigned int i; float f; } c; c.i = ((unsigned int)u) << 16; return c.f;
}
DEV unsigned short f2bf(float f) {
    union { float f; unsigned int i; } c; c.f = f;
    unsigned int r = c.i + 0x7fffu + ((c.i >> 16) & 1u);   // RNE
    return (unsigned short)(r >> 16);
}

// async global(16B/lane) -> LDS (wave-uniform base; HW adds lane*16)
DEV void gload16(const unsigned short* g, void* l) {
    __builtin_amdgcn_global_load_lds(
        (const __attribute__((address_space(1))) void*)g,
        (__attribute__((address_space(3))) void*)l, 16, 0, 0);
}

// ---------------------------------------------------------------------------
// All weight transposes (fp32 [R][C] -> bf16 [C][R]) in ONE dispatch.
// ---------------------------------------------------------------------------
__global__ __launch_bounds__(256)
void transpose_all(const float* __restrict__ Wq, const float* __restrict__ Wk,
                   const float* __restrict__ Wv, const float* __restrict__ Wo,
                   const float* __restrict__ W1, const float* __restrict__ W2,
                   unsigned short* __restrict__ wqkvT, unsigned short* __restrict__ woT,
                   unsigned short* __restrict__ w1T, unsigned short* __restrict__ w2aT,
                   unsigned short* __restrict__ w2bT) {
    __shared__ float tile[32][33];
    int bid = blockIdx.x;
    const float* in; unsigned short* out; int R, C, gx;
    if (bid < 576)        { in = Wq; out = wqkvT;           R = 768;  C = 768;  gx = 24; }
    else if (bid < 1152)  { in = Wk; out = wqkvT + 589824;  R = 768;  C = 768;  gx = 24; bid -= 576; }
    else if (bid < 1728)  { in = Wv; out = wqkvT + 1179648; R = 768;  C = 768;  gx = 24; bid -= 1152; }
    else if (bid < 2304)  { in = Wo; out = woT;             R = 768;  C = 768;  gx = 24; bid -= 1728; }
    else if (bid < 4608)  { in = W1; out = w1T;             R = 768;  C = 3072; gx = 96; bid -= 2304; }
    else if (bid < 5760)  { in = W2; out = w2aT;            R = 1536; C = 768;  gx = 24; bid -= 4608; }
    else                  { in = W2 + (size_t)1536 * 768; out = w2bT; R = 1536; C = 768; gx = 24; bid -= 5760; }
    const int c0 = (bid % gx) * 32, r0 = (bid / gx) * 32;
    const int tx = threadIdx.x, ty = threadIdx.y;          // (32, 8)
    #pragma unroll
    for (int i = 0; i < 32; i += 8)
        tile[ty + i][tx] = in[(size_t)(r0 + ty + i) * C + c0 + tx];
    __syncthreads();
    #pragma unroll
    for (int i = 0; i < 32; i += 8)
        out[(size_t)(c0 + ty + i) * R + r0 + tx] = f2bf(tile[tx][ty + i]);
}

// ---------------------------------------------------------------------------
// LayerNorm over D=768 -> bf16. BF16IN: input dtype.
// ---------------------------------------------------------------------------
template <int BF16IN>
__global__ __launch_bounds__(256)
void ln_kernel(const void* __restrict__ xin, const float* __restrict__ g,
               const float* __restrict__ bvec, unsigned short* __restrict__ out) {
    __shared__ float red[4];
    const int tid = threadIdx.x;
    const size_t base = (size_t)blockIdx.x * Dd;
    float v[3];
    #pragma unroll
    for (int i = 0; i < 3; ++i) {
        const size_t idx = base + tid + i * 256;
        if (BF16IN) v[i] = bf2f(((const unsigned short*)xin)[idx]);
        else        v[i] = ((const float*)xin)[idx];
    }
    float s = v[0] + v[1] + v[2];
    #pragma unroll
    for (int o = 32; o >= 1; o >>= 1) s += __shfl_xor(s, o);
    if ((tid & 63) == 0) red[tid >> 6] = s;
    __syncthreads();
    s = red[0] + red[1] + red[2] + red[3];
    const float mu = s * (1.0f / Dd);
    __syncthreads();
    float q = 0.f;
    #pragma unroll
    for (int i = 0; i < 3; ++i) { const float d = v[i] - mu; q += d * d; }
    #pragma unroll
    for (int o = 32; o >= 1; o >>= 1) q += __shfl_xor(q, o);
    if ((tid & 63) == 0) red[tid >> 6] = q;
    __syncthreads();
    q = red[0] + red[1] + red[2] + red[3];
    const float rstd = rsqrtf(q * (1.0f / Dd) + 1e-5f);
    #pragma unroll
    for (int i = 0; i < 3; ++i) {
        const int c = tid + i * 256;
        out[base + c] = f2bf((v[i] - mu) * rstd * g[c] + bvec[c]);
    }
}

// ---------------------------------------------------------------------------
// m97-form GEMM, BK=64, 32x32x16 MFMA: 128x128, 4 waves (2x2), 32KB LDS,
// 2 x __syncthreads per K-tile, compiler-scheduled waits, (256,4).
// Per K-tile per wave: 4 kk-steps x {2 A + 2 B ds_read_b128, 4 MFMA}.
// LDS rows 128B; slot c of row r holds global granule c^(r&7).
// ---------------------------------------------------------------------------
#define EPI_QKV  0   // out bf16 Q/K/V triple (each M*768), elu+1 on Q,K
#define EPI_X2   1   // out bf16 = acc*zinv[row] + bias[col] + f32res[row,col]
#define EPI_GELU 2   // out bf16 = gelu(acc + bias[col])
#define EPI_OUT1 3   // out f32  = acc + bias[col] + bf16res[row,col]
#define EPI_OUT2 4   // out f32 += acc

template <int EPI, int K, int PB>
__global__ __launch_bounds__(256, 4)
void gemm97(const unsigned short* __restrict__ A,
            const unsigned short* __restrict__ BT,
            const float* __restrict__ bias,
            const void* __restrict__ res,
            const float* __restrict__ zv,
            void* __restrict__ out, int N) {
    const int NTile = N >> 7;
    const int nwg = gridDim.x;
    int wg = blockIdx.x;
    wg = (wg & 7) * (nwg >> 3) + (wg >> 3);       // XCD-contiguous (nwg % 8 == 0)
    const int nt = wg % NTile, mt = wg / NTile;
    const int m0 = mt * 128, n0 = nt * 128;
    const int tid = threadIdx.x;
    const int lane = tid & 63, w = tid >> 6;
    const int wm = w >> 1, wn = w & 1;            // 2 x 2 waves
    const int l31 = lane & 31, lg = lane >> 5;    // 32x32 frag coords

    __shared__ __align__(16) char lds[32768];     // A rows @ r*128, B @ 16384 + r*128

    const unsigned short* BTb = PB ? (BT + (size_t)(m0 >> 13) * 768 * 768) : BT;

    // staging: 32 groups of 1KB (8 rows x 128B each); lane l -> row l>>3,
    // LDS slot l&7, source granule (l&7)^(l>>3)
    const int srow = lane >> 3;
    const int gsrc = (lane & 7) ^ srow;

    f32x16 acc[2][2] = {};

    for (int kt = 0; kt < K; kt += 64) {
        #pragma unroll
        for (int j = 0; j < 8; ++j) {
            const int grp = w * 8 + j;            // 0..15 = A, 16..31 = B
            const unsigned short* src = (grp < 16)
                ? A   + (size_t)(m0 + grp * 8 + srow) * K + kt + gsrc * 8
                : BTb + (size_t)(n0 + (grp - 16) * 8 + srow) * K + kt + gsrc * 8;
            gload16(src, lds + grp * 1024);
        }
        __syncthreads();                          // compiler drains vmcnt before barrier

        const char* bA = lds + (wm * 64) * 128;
        const char* bB = lds + 16384 + (wn * 64) * 128;
        #pragma unroll
        for (int kk = 0; kk < 4; ++kk) {
            const int g = kk * 2 + lg;            // granule within 8 (K=64)
            const int sl = g ^ (l31 & 7);         // swizzled slot
            s16x8 af[2], bf[2];
            #pragma unroll
            for (int i = 0; i < 2; ++i) {
                af[i] = *(const s16x8*)(bA + (i * 32 + l31) * 128 + (sl << 4));
                bf[i] = *(const s16x8*)(bB + (i * 32 + l31) * 128 + (sl << 4));
            }
            #pragma unroll
            for (int i = 0; i < 2; ++i)
                #pragma unroll
                for (int j = 0; j < 2; ++j)
                    acc[i][j] = __builtin_amdgcn_mfma_f32_32x32x16_bf16(af[i], bf[j], acc[i][j], 0, 0, 0);
        }
        __syncthreads();                          // all reads retired before restage
    }

    // epilogue: C/D mapping col = lane&31, row = (reg&3) + 8*(reg>>2) + 4*(lane>>5)
    #pragma unroll
    for (int mi = 0; mi < 2; ++mi) {
        #pragma unroll
        for (int nj = 0; nj < 2; ++nj) {
            const int col = n0 + wn * 64 + nj * 32 + l31;
            #pragma unroll
            for (int reg = 0; reg < 16; ++reg) {
                const int row = m0 + wm * 64 + mi * 32 + (reg & 3) + 8 * (reg >> 2) + 4 * lg;
                float v = acc[mi][nj][reg];
                if (EPI == EPI_QKV) {
                    const int which = col / 768;
                    const int cc = col - which * 768;
                    if (which < 2) v = (v > 0.f) ? (v + 1.f) : __expf(v);   // elu(v)+1
                    ((unsigned short*)out)[(size_t)which * (Mrows * Dd) + (size_t)row * Dd + cc] = f2bf(v);
                } else if (EPI == EPI_X2) {
                    v = v * zv[row] + bias[col] + ((const float*)res)[(size_t)row * N + col];
                    ((unsigned short*)out)[(size_t)row * N + col] = f2bf(v);
                } else if (EPI == EPI_GELU) {
                    v += bias[col];
                    v = 0.5f * v * (1.0f + erff(v * 0.70710678118654752f));
                    ((unsigned short*)out)[(size_t)row * N + col] = f2bf(v);
                } else if (EPI == EPI_OUT1) {
                    v += bias[col] + bf2f(((const unsigned short*)res)[(size_t)row * N + col]);
                    ((float*)out)[(size_t)row * N + col] = v;
                } else {  // EPI_OUT2
                    ((float*)out)[(size_t)row * N + col] += v;
                }
            }
        }
    }
}

// ---------------------------------------------------------------------------
// Partial KV + partial Ksum per 1024-t chunk.
// ---------------------------------------------------------------------------
__global__ __launch_bounds__(256)
void kv_partial(const unsigned short* __restrict__ Km, const unsigned short* __restrict__ Vm,
                float* __restrict__ part, float* __restrict__ pksum) {
    const int ck = blockIdx.x, bh = blockIdx.y;
    const int b = bh / Hh, h = bh - b * Hh;
    const int tid = threadIdx.x;
    const int e = tid & 63, dg = tid >> 6;
    __shared__ float sK[32][64], sV[32][64];
    float acc[16] = {};
    float ksacc = 0.f;
    const size_t rowbase = ((size_t)b * Tt + (size_t)ck * 1024) * Dd + h * 64;
    const int rw = tid >> 3, cv = (tid & 7) * 8;
    for (int ts = 0; ts < 1024; ts += 32) {
        const s16x8 k8 = *(const s16x8*)(Km + rowbase + (size_t)(ts + rw) * Dd + cv);
        const s16x8 v8 = *(const s16x8*)(Vm + rowbase + (size_t)(ts + rw) * Dd + cv);
        float kf[8], vf[8];
        #pragma unroll
        for (int j = 0; j < 8; ++j) {
            kf[j] = bf2f((unsigned short)k8[j]);
            vf[j] = bf2f((unsigned short)v8[j]);
        }
        __syncthreads();
        *(float4*)(&sK[rw][cv])     = *(const float4*)&kf[0];
        *(float4*)(&sK[rw][cv + 4]) = *(const float4*)&kf[4];
        *(float4*)(&sV[rw][cv])     = *(const float4*)&vf[0];
        *(float4*)(&sV[rw][cv + 4]) = *(const float4*)&vf[4];
        __syncthreads();
        #pragma unroll 4
        for (int tt = 0; tt < 32; ++tt) {
            const float vv = sV[tt][e];
            const float4* kp = (const float4*)(&sK[tt][dg * 16]);
            const float4 k0 = kp[0], k1 = kp[1], k2 = kp[2], k3 = kp[3];
            acc[0]  += k0.x * vv; acc[1]  += k0.y * vv; acc[2]  += k0.z * vv; acc[3]  += k0.w * vv;
            acc[4]  += k1.x * vv; acc[5]  += k1.y * vv; acc[6]  += k1.z * vv; acc[7]  += k1.w * vv;
            acc[8]  += k2.x * vv; acc[9]  += k2.y * vv; acc[10] += k2.z * vv; acc[11] += k2.w * vv;
            acc[12] += k3.x * vv; acc[13] += k3.y * vv; acc[14] += k3.z * vv; acc[15] += k3.w * vv;
        }
        if (dg == 0) {
            #pragma unroll 4
            for (int tt = 0; tt < 32; ++tt) ksacc += sK[tt][e];
        }
    }
    float* op = part + ((size_t)bh * 8 + ck) * 4096 + (size_t)dg * 16 * 64 + e;
    #pragma unroll
    for (int i = 0; i < 16; ++i) op[(size_t)i * 64] = acc[i];
    if (dg == 0) pksum[((size_t)bh * 8 + ck) * 64 + e] = ksacc;
}

__global__ __launch_bounds__(256)
void kv_reduce(const float* __restrict__ part, const float* __restrict__ pksum,
               float* __restrict__ kv, float* __restrict__ ksum) {
    const int bh = blockIdx.x;
    const int tid = threadIdx.x;
    #pragma unroll
    for (int j = 0; j < 16; ++j) {
        const int i = j * 256 + tid;
        float s = 0.f;
        #pragma unroll
        for (int c = 0; c < 8; ++c) s += part[((size_t)bh * 8 + c) * 4096 + i];
        kv[(size_t)bh * 4096 + i] = s;
    }
    if (tid < 64) {
        float s = 0.f;
        #pragma unroll
        for (int c = 0; c < 8; ++c) s += pksum[((size_t)bh * 8 + c) * 64 + tid];
        ksum[(size_t)bh * 64 + tid] = s;
    }
}

// ---------------------------------------------------------------------------
// zinv[row] = 1 / (sum_c Q[row,c] * Ksum[b, c] + eps). One block per row.
// ---------------------------------------------------------------------------
__global__ __launch_bounds__(256)
void z_kernel(const unsigned short* __restrict__ Q, const float* __restrict__ ksum,
              float* __restrict__ zinv) {
    __shared__ float red[4];
    const int row = blockIdx.x;
    const int b = row >> 13;
    const int tid = threadIdx.x;
    const size_t base = (size_t)row * Dd;
    const float* ks = ksum + (size_t)b * Hh * 64;   // [768] contiguous (h*64+d)
    float s = 0.f;
    #pragma unroll
    for (int i = 0; i < 3; ++i) {
        const int c = i * 256 + tid;
        s += bf2f(Q[base + c]) * ks[c];
    }
    #pragma unroll
    for (int o = 32; o >= 1; o >>= 1) s += __shfl_xor(s, o);
    if ((tid & 63) == 0) red[tid >> 6] = s;
    __syncthreads();
    if (tid == 0) {
        const float z = red[0] + red[1] + red[2] + red[3] + 1e-6f;
        zinv[row] = 1.0f / z;
    }
}

// ---------------------------------------------------------------------------
// W2T[b][n][h*64+d] = sum_e KV_bh[d][e] * woT[n][h*64+e]
// ---------------------------------------------------------------------------
__global__ __launch_bounds__(256)
void w2_build(const float* __restrict__ kvf, const unsigned short* __restrict__ woT,
              unsigned short* __restrict__ W2T) {
    const int bh = blockIdx.x, ny = blockIdx.y;
    const int b = bh / Hh, h = bh - b * Hh;
    __shared__ float sKV[64][65];
    const int tid = threadIdx.x;
    for (int i = tid; i < 4096; i += 256) sKV[i >> 6][i & 63] = kvf[(size_t)bh * 4096 + i];
    __syncthreads();
    const int d = tid & 63, ng = tid >> 6;
    #pragma unroll 4
    for (int i = 0; i < 48; ++i) {
        const int n = ny * 192 + i * 4 + ng;
        const unsigned short* wr = woT + (size_t)n * Dd + h * 64;
        float a = 0.f;
        #pragma unroll
        for (int e = 0; e < 64; ++e) a += bf2f(wr[e]) * sKV[d][e];
        W2T[((size_t)b * Dd + n) * Dd + h * 64 + d] = f2bf(a);
    }
}

// ---------------------------------------------------------------------------
extern "C" void kernel_launch(void* const* d_in, const int* in_sizes, int n_in,
                              void* d_out, int out_size, void* d_ws, size_t ws_size,
                              hipStream_t stream) {
    (void)in_sizes; (void)n_in; (void)out_size; (void)ws_size;
    const float* x    = (const float*)d_in[0];
    const float* Wq   = (const float*)d_in[1];
    const float* Wk   = (const float*)d_in[2];
    const float* Wv   = (const float*)d_in[3];
    const float* Wo   = (const float*)d_in[4];
    const float* bo   = (const float*)d_in[5];
    const float* ln1g = (const float*)d_in[6];
    const float* ln1b = (const float*)d_in[7];
    const float* ln2g = (const float*)d_in[8];
    const float* ln2b = (const float*)d_in[9];
    const float* W1   = (const float*)d_in[10];
    const float* b1   = (const float*)d_in[11];
    const float* W2   = (const float*)d_in[12];
    const float* b2   = (const float*)d_in[13];
    float* outp = (float*)d_out;

    char* ws = (char*)d_ws;
    const size_t SZ = Mrows * Dd * 2;                           // bf16 [M][768] slot
    unsigned short* xn = (unsigned short*)(ws + 0);             // s0: LN out
    unsigned short* Qb = (unsigned short*)(ws + SZ);            // s1: Q, later ff1-lo
    unsigned short* Kb = (unsigned short*)(ws + 2 * SZ);        // s2: K, later ff1-hi
    unsigned short* Vb = (unsigned short*)(ws + 3 * SZ);        // s3: V, later x2 bf16
    char* p = ws + 4 * SZ;
    float* part  = (float*)p;  p += (size_t)48 * 8 * 4096 * 4;  // 6.3 MB (later: W2T)
    float* kvf   = (float*)p;  p += (size_t)48 * 4096 * 4;
    float* ksumf = (float*)p;  p += (size_t)48 * 64 * 4;
    unsigned short* wqkvT = (unsigned short*)p; p += (size_t)2304 * 768 * 2;
    unsigned short* woT   = (unsigned short*)p; p += (size_t)768 * 768 * 2;
    unsigned short* w1T   = (unsigned short*)p; p += (size_t)3072 * 768 * 2;
    unsigned short* w2aT  = (unsigned short*)p; p += (size_t)768 * 1536 * 2;
    unsigned short* w2bT  = (unsigned short*)p; p += (size_t)768 * 1536 * 2;
    float* pksum = (float*)p;  p += (size_t)48 * 8 * 64 * 4;
    float* zinv  = (float*)p;  p += (size_t)Mrows * 4;          // 131 KB
    unsigned short* W2T = (unsigned short*)part;   // part dead after kv_reduce
    unsigned short* ff1 = Qb;                      // M x 1536 bf16 = slots s1+s2
    unsigned short* x2b = Vb;

    const dim3 blk(256);
    const dim3 tb(32, 8);

    // 1) all weight transposes in one dispatch
    transpose_all<<<6912, tb, 0, stream>>>(Wq, Wk, Wv, Wo, W1, W2,
                                           wqkvT, woT, w1T, w2aT, w2bT);

    // 2) LN1
    ln_kernel<0><<<32768, blk, 0, stream>>>(x, ln1g, ln1b, xn);

    // 3) fused QKV projection (N=2304): 256 mt x 18 nt = 4608 wg
    gemm97<EPI_QKV, 768, 0><<<4608, blk, 0, stream>>>(xn, wqkvT, nullptr, nullptr, nullptr, Qb, 2304);

    // 4) linear-attention stats: KV and Ksum
    kv_partial<<<dim3(8, 48), blk, 0, stream>>>(Kb, Vb, part, pksum);
    kv_reduce<<<48, blk, 0, stream>>>(part, pksum, kvf, ksumf);

    // 5) zinv[row] = 1/(Q.Ksum + eps); W2 = KV @ Wo (per b,h)
    z_kernel<<<32768, blk, 0, stream>>>(Qb, ksumf, zinv);
    w2_build<<<dim3(48, 4), blk, 0, stream>>>(kvf, woT, W2T);

    // 6) x2 = (Q@W2)*zinv + bo + x : 256 x 6 = 1536 wg, per-batch weights
    gemm97<EPI_X2, 768, 1><<<1536, blk, 0, stream>>>(Qb, W2T, bo, x, zinv, x2b, 768);

    // 7) LN2
    ln_kernel<1><<<32768, blk, 0, stream>>>(x2b, ln2g, ln2b, xn);

    // 8) FFN in two halves (ff1 = M x 1536 bf16 in s1+s2)
    gemm97<EPI_GELU, 768, 0><<<3072, blk, 0, stream>>>(xn, w1T, b1, nullptr, nullptr, ff1, 1536);
    gemm97<EPI_OUT1, 1536, 0><<<1536, blk, 0, stream>>>(ff1, w2aT, b2, x2b, nullptr, outp, 768);
    gemm97<EPI_GELU, 768, 0><<<3072, blk, 0, stream>>>(xn, w1T + (size_t)1536 * 768,
                                                       b1 + 1536, nullptr, nullptr, ff1, 1536);
    gemm97<EPI_OUT2, 1536, 0><<<1536, blk, 0, stream>>>(ff1, w2bT, nullptr, nullptr, nullptr, outp, 768);
}

// Round 19
// 875.403 us; speedup vs baseline: 1.0742x; 1.0742x over previous
//
#include <hip/hip_runtime.h>
#include <math.h>

// LinearBlock: x -> LN1 -> QKV -> linear attention -> Wo+bias+res -> LN2 -> FFN(gelu) -> +res
// B=4, T=8192, D=768, H=12, HD=64, DFF=3072. fp32 in/out; bf16 MFMA internally.
//
// Round-19: restore R16 verbatim (876.6us, session best). R18's FFN fusion needed
// 4 free bf16 slots (ff1-lo+hi simultaneously) which don't exist while xn/x2b are
// live -- it clobbered x2b and read the wrong ff1 half. Ledger of falsified axes:
// explicit pipelines (R4-R11), 32x32 MFMA (R17, bank conflicts), launch-bounds
// deviations (R13/R14), LDS-heavy merges (R15), cross-slot fusions (R18).

#define DEV __device__ __forceinline__

typedef __attribute__((ext_vector_type(8))) short s16x8;   // 8 x bf16 (4 VGPRs)
typedef __attribute__((ext_vector_type(4))) float f32x4;   // MFMA accumulator

static constexpr int    Bb   = 4;
static constexpr int    Tt   = 8192;
static constexpr int    Dd   = 768;
static constexpr int    Hh   = 12;
static constexpr size_t Mrows = (size_t)Bb * Tt;           // 32768

DEV float bf2f(unsigned short u) {
    union { unsigned int i; float f; } c; c.i = ((unsigned int)u) << 16; return c.f;
}
DEV unsigned short f2bf(float f) {
    union { float f; unsigned int i; } c; c.f = f;
    unsigned int r = c.i + 0x7fffu + ((c.i >> 16) & 1u);   // RNE
    return (unsigned short)(r >> 16);
}

// async global(16B/lane) -> LDS (wave-uniform base; HW adds lane*16)
DEV void gload16(const unsigned short* g, void* l) {
    __builtin_amdgcn_global_load_lds(
        (const __attribute__((address_space(1))) void*)g,
        (__attribute__((address_space(3))) void*)l, 16, 0, 0);
}

// ---------------------------------------------------------------------------
// All weight transposes (fp32 [R][C] -> bf16 [C][R]) in ONE dispatch.
// ---------------------------------------------------------------------------
__global__ __launch_bounds__(256)
void transpose_all(const float* __restrict__ Wq, const float* __restrict__ Wk,
                   const float* __restrict__ Wv, const float* __restrict__ Wo,
                   const float* __restrict__ W1, const float* __restrict__ W2,
                   unsigned short* __restrict__ wqkvT, unsigned short* __restrict__ woT,
                   unsigned short* __restrict__ w1T, unsigned short* __restrict__ w2aT,
                   unsigned short* __restrict__ w2bT) {
    __shared__ float tile[32][33];
    int bid = blockIdx.x;
    const float* in; unsigned short* out; int R, C, gx;
    if (bid < 576)        { in = Wq; out = wqkvT;           R = 768;  C = 768;  gx = 24; }
    else if (bid < 1152)  { in = Wk; out = wqkvT + 589824;  R = 768;  C = 768;  gx = 24; bid -= 576; }
    else if (bid < 1728)  { in = Wv; out = wqkvT + 1179648; R = 768;  C = 768;  gx = 24; bid -= 1152; }
    else if (bid < 2304)  { in = Wo; out = woT;             R = 768;  C = 768;  gx = 24; bid -= 1728; }
    else if (bid < 4608)  { in = W1; out = w1T;             R = 768;  C = 3072; gx = 96; bid -= 2304; }
    else if (bid < 5760)  { in = W2; out = w2aT;            R = 1536; C = 768;  gx = 24; bid -= 4608; }
    else                  { in = W2 + (size_t)1536 * 768; out = w2bT; R = 1536; C = 768; gx = 24; bid -= 5760; }
    const int c0 = (bid % gx) * 32, r0 = (bid / gx) * 32;
    const int tx = threadIdx.x, ty = threadIdx.y;          // (32, 8)
    #pragma unroll
    for (int i = 0; i < 32; i += 8)
        tile[ty + i][tx] = in[(size_t)(r0 + ty + i) * C + c0 + tx];
    __syncthreads();
    #pragma unroll
    for (int i = 0; i < 32; i += 8)
        out[(size_t)(c0 + ty + i) * R + r0 + tx] = f2bf(tile[tx][ty + i]);
}

// ---------------------------------------------------------------------------
// LayerNorm over D=768 -> bf16. BF16IN: input dtype.
// ---------------------------------------------------------------------------
template <int BF16IN>
__global__ __launch_bounds__(256)
void ln_kernel(const void* __restrict__ xin, const float* __restrict__ g,
               const float* __restrict__ bvec, unsigned short* __restrict__ out) {
    __shared__ float red[4];
    const int tid = threadIdx.x;
    const size_t base = (size_t)blockIdx.x * Dd;
    float v[3];
    #pragma unroll
    for (int i = 0; i < 3; ++i) {
        const size_t idx = base + tid + i * 256;
        if (BF16IN) v[i] = bf2f(((const unsigned short*)xin)[idx]);
        else        v[i] = ((const float*)xin)[idx];
    }
    float s = v[0] + v[1] + v[2];
    #pragma unroll
    for (int o = 32; o >= 1; o >>= 1) s += __shfl_xor(s, o);
    if ((tid & 63) == 0) red[tid >> 6] = s;
    __syncthreads();
    s = red[0] + red[1] + red[2] + red[3];
    const float mu = s * (1.0f / Dd);
    __syncthreads();
    float q = 0.f;
    #pragma unroll
    for (int i = 0; i < 3; ++i) { const float d = v[i] - mu; q += d * d; }
    #pragma unroll
    for (int o = 32; o >= 1; o >>= 1) q += __shfl_xor(q, o);
    if ((tid & 63) == 0) red[tid >> 6] = q;
    __syncthreads();
    q = red[0] + red[1] + red[2] + red[3];
    const float rstd = rsqrtf(q * (1.0f / Dd) + 1e-5f);
    #pragma unroll
    for (int i = 0; i < 3; ++i) {
        const int c = tid + i * 256;
        out[base + c] = f2bf((v[i] - mu) * rstd * g[c] + bvec[c]);
    }
}

// ---------------------------------------------------------------------------
// m97-form GEMM, BK=64 (frozen R16 optimum): 128x128, 4 waves (2x2), 32KB LDS,
// 2 x __syncthreads per 64-wide K-tile, two kk-subpasses of 16 MFMA each,
// compiler-scheduled waits, __launch_bounds__(256,4) => VGPR 64, occ ~34%.
// C[M,N] = A[M,K] @ BT[N,K]^T, bf16 in, fp32 acc, fused epilogue.
// LDS rows 128B; slot c of row r holds global granule c^(r&7)
// (write via per-lane source granule (l&7)^(l>>3); read same XOR) -> 0 conflicts.
// ---------------------------------------------------------------------------
#define EPI_QKV  0   // out bf16 Q/K/V triple (each M*768), elu+1 on Q,K
#define EPI_X2   1   // out bf16 = acc*zinv[row] + bias[col] + f32res[row,col]
#define EPI_GELU 2   // out bf16 = gelu(acc + bias[col])
#define EPI_OUT1 3   // out f32  = acc + bias[col] + bf16res[row,col]
#define EPI_OUT2 4   // out f32 += acc

template <int EPI, int K, int PB>
__global__ __launch_bounds__(256, 4)
void gemm97(const unsigned short* __restrict__ A,
            const unsigned short* __restrict__ BT,
            const float* __restrict__ bias,
            const void* __restrict__ res,
            const float* __restrict__ zv,
            void* __restrict__ out, int N) {
    const int NTile = N >> 7;
    const int nwg = gridDim.x;
    int wg = blockIdx.x;
    wg = (wg & 7) * (nwg >> 3) + (wg >> 3);       // XCD-contiguous (nwg % 8 == 0)
    const int nt = wg % NTile, mt = wg / NTile;
    const int m0 = mt * 128, n0 = nt * 128;
    const int tid = threadIdx.x;
    const int lane = tid & 63, w = tid >> 6;
    const int wm = w >> 1, wn = w & 1;            // 2 x 2 waves
    const int l15 = lane & 15, lk = lane >> 4;

    __shared__ __align__(16) char lds[32768];     // A rows @ r*128, B @ 16384 + r*128

    const unsigned short* BTb = PB ? (BT + (size_t)(m0 >> 13) * 768 * 768) : BT;

    // staging: 32 groups of 1KB (8 rows x 128B each); lane l -> row l>>3,
    // LDS slot l&7, source granule (l&7)^(l>>3)
    const int srow = lane >> 3;
    const int gsrc = (lane & 7) ^ srow;
    const int sw7  = l15 & 7;                     // read-side granule XOR

    f32x4 acc[4][4] = {};

    for (int kt = 0; kt < K; kt += 64) {
        #pragma unroll
        for (int j = 0; j < 8; ++j) {
            const int grp = w * 8 + j;            // 0..15 = A, 16..31 = B
            const unsigned short* src = (grp < 16)
                ? A   + (size_t)(m0 + grp * 8 + srow) * K + kt + gsrc * 8
                : BTb + (size_t)(n0 + (grp - 16) * 8 + srow) * K + kt + gsrc * 8;
            gload16(src, lds + grp * 1024);
        }
        __syncthreads();                          // compiler drains vmcnt before barrier

        const char* bA = lds + (wm * 64) * 128;
        const char* bB = lds + 16384 + (wn * 64) * 128;
        #pragma unroll
        for (int kk = 0; kk < 2; ++kk) {
            s16x8 af[4], bf[4];
            #pragma unroll
            for (int i = 0; i < 4; ++i) {
                af[i] = *(const s16x8*)(bA + (i * 16 + l15) * 128 +
                          ((((kk << 2) | lk) ^ sw7) << 4));
                bf[i] = *(const s16x8*)(bB + (i * 16 + l15) * 128 +
                          ((((kk << 2) | lk) ^ sw7) << 4));
            }
            #pragma unroll
            for (int i = 0; i < 4; ++i)
                #pragma unroll
                for (int j = 0; j < 4; ++j)
                    acc[i][j] = __builtin_amdgcn_mfma_f32_16x16x32_bf16(af[i], bf[j], acc[i][j], 0, 0, 0);
        }
        __syncthreads();                          // all reads retired before restage
    }

    // epilogue: D frag mapping col = lane&15, row = (lane>>4)*4 + r
    #pragma unroll
    for (int mi = 0; mi < 4; ++mi) {
        #pragma unroll
        for (int nj = 0; nj < 4; ++nj) {
            const int col = n0 + wn * 64 + nj * 16 + l15;
            #pragma unroll
            for (int r = 0; r < 4; ++r) {
                const int row = m0 + wm * 64 + mi * 16 + lk * 4 + r;
                float v = acc[mi][nj][r];
                if (EPI == EPI_QKV) {
                    const int which = col / 768;
                    const int cc = col - which * 768;
                    if (which < 2) v = (v > 0.f) ? (v + 1.f) : __expf(v);   // elu(v)+1
                    ((unsigned short*)out)[(size_t)which * (Mrows * Dd) + (size_t)row * Dd + cc] = f2bf(v);
                } else if (EPI == EPI_X2) {
                    v = v * zv[row] + bias[col] + ((const float*)res)[(size_t)row * N + col];
                    ((unsigned short*)out)[(size_t)row * N + col] = f2bf(v);
                } else if (EPI == EPI_GELU) {
                    v += bias[col];
                    v = 0.5f * v * (1.0f + erff(v * 0.70710678118654752f));
                    ((unsigned short*)out)[(size_t)row * N + col] = f2bf(v);
                } else if (EPI == EPI_OUT1) {
                    v += bias[col] + bf2f(((const unsigned short*)res)[(size_t)row * N + col]);
                    ((float*)out)[(size_t)row * N + col] = v;
                } else {  // EPI_OUT2
                    ((float*)out)[(size_t)row * N + col] += v;
                }
            }
        }
    }
}

// ---------------------------------------------------------------------------
// Partial KV + partial Ksum per 1024-t chunk.
// ---------------------------------------------------------------------------
__global__ __launch_bounds__(256)
void kv_partial(const unsigned short* __restrict__ Km, const unsigned short* __restrict__ Vm,
                float* __restrict__ part, float* __restrict__ pksum) {
    const int ck = blockIdx.x, bh = blockIdx.y;
    const int b = bh / Hh, h = bh - b * Hh;
    const int tid = threadIdx.x;
    const int e = tid & 63, dg = tid >> 6;
    __shared__ float sK[32][64], sV[32][64];
    float acc[16] = {};
    float ksacc = 0.f;
    const size_t rowbase = ((size_t)b * Tt + (size_t)ck * 1024) * Dd + h * 64;
    const int rw = tid >> 3, cv = (tid & 7) * 8;
    for (int ts = 0; ts < 1024; ts += 32) {
        const s16x8 k8 = *(const s16x8*)(Km + rowbase + (size_t)(ts + rw) * Dd + cv);
        const s16x8 v8 = *(const s16x8*)(Vm + rowbase + (size_t)(ts + rw) * Dd + cv);
        float kf[8], vf[8];
        #pragma unroll
        for (int j = 0; j < 8; ++j) {
            kf[j] = bf2f((unsigned short)k8[j]);
            vf[j] = bf2f((unsigned short)v8[j]);
        }
        __syncthreads();
        *(float4*)(&sK[rw][cv])     = *(const float4*)&kf[0];
        *(float4*)(&sK[rw][cv + 4]) = *(const float4*)&kf[4];
        *(float4*)(&sV[rw][cv])     = *(const float4*)&vf[0];
        *(float4*)(&sV[rw][cv + 4]) = *(const float4*)&vf[4];
        __syncthreads();
        #pragma unroll 4
        for (int tt = 0; tt < 32; ++tt) {
            const float vv = sV[tt][e];
            const float4* kp = (const float4*)(&sK[tt][dg * 16]);
            const float4 k0 = kp[0], k1 = kp[1], k2 = kp[2], k3 = kp[3];
            acc[0]  += k0.x * vv; acc[1]  += k0.y * vv; acc[2]  += k0.z * vv; acc[3]  += k0.w * vv;
            acc[4]  += k1.x * vv; acc[5]  += k1.y * vv; acc[6]  += k1.z * vv; acc[7]  += k1.w * vv;
            acc[8]  += k2.x * vv; acc[9]  += k2.y * vv; acc[10] += k2.z * vv; acc[11] += k2.w * vv;
            acc[12] += k3.x * vv; acc[13] += k3.y * vv; acc[14] += k3.z * vv; acc[15] += k3.w * vv;
        }
        if (dg == 0) {
            #pragma unroll 4
            for (int tt = 0; tt < 32; ++tt) ksacc += sK[tt][e];
        }
    }
    float* op = part + ((size_t)bh * 8 + ck) * 4096 + (size_t)dg * 16 * 64 + e;
    #pragma unroll
    for (int i = 0; i < 16; ++i) op[(size_t)i * 64] = acc[i];
    if (dg == 0) pksum[((size_t)bh * 8 + ck) * 64 + e] = ksacc;
}

__global__ __launch_bounds__(256)
void kv_reduce(const float* __restrict__ part, const float* __restrict__ pksum,
               float* __restrict__ kv, float* __restrict__ ksum) {
    const int bh = blockIdx.x;
    const int tid = threadIdx.x;
    #pragma unroll
    for (int j = 0; j < 16; ++j) {
        const int i = j * 256 + tid;
        float s = 0.f;
        #pragma unroll
        for (int c = 0; c < 8; ++c) s += part[((size_t)bh * 8 + c) * 4096 + i];
        kv[(size_t)bh * 4096 + i] = s;
    }
    if (tid < 64) {
        float s = 0.f;
        #pragma unroll
        for (int c = 0; c < 8; ++c) s += pksum[((size_t)bh * 8 + c) * 64 + tid];
        ksum[(size_t)bh * 64 + tid] = s;
    }
}

// ---------------------------------------------------------------------------
// zinv[row] = 1 / (sum_c Q[row,c] * Ksum[b, c] + eps). One block per row.
// ---------------------------------------------------------------------------
__global__ __launch_bounds__(256)
void z_kernel(const unsigned short* __restrict__ Q, const float* __restrict__ ksum,
              float* __restrict__ zinv) {
    __shared__ float red[4];
    const int row = blockIdx.x;
    const int b = row >> 13;
    const int tid = threadIdx.x;
    const size_t base = (size_t)row * Dd;
    const float* ks = ksum + (size_t)b * Hh * 64;   // [768] contiguous (h*64+d)
    float s = 0.f;
    #pragma unroll
    for (int i = 0; i < 3; ++i) {
        const int c = i * 256 + tid;
        s += bf2f(Q[base + c]) * ks[c];
    }
    #pragma unroll
    for (int o = 32; o >= 1; o >>= 1) s += __shfl_xor(s, o);
    if ((tid & 63) == 0) red[tid >> 6] = s;
    __syncthreads();
    if (tid == 0) {
        const float z = red[0] + red[1] + red[2] + red[3] + 1e-6f;
        zinv[row] = 1.0f / z;
    }
}

// ---------------------------------------------------------------------------
// W2T[b][n][h*64+d] = sum_e KV_bh[d][e] * woT[n][h*64+e]
// ---------------------------------------------------------------------------
__global__ __launch_bounds__(256)
void w2_build(const float* __restrict__ kvf, const unsigned short* __restrict__ woT,
              unsigned short* __restrict__ W2T) {
    const int bh = blockIdx.x, ny = blockIdx.y;
    const int b = bh / Hh, h = bh - b * Hh;
    __shared__ float sKV[64][65];
    const int tid = threadIdx.x;
    for (int i = tid; i < 4096; i += 256) sKV[i >> 6][i & 63] = kvf[(size_t)bh * 4096 + i];
    __syncthreads();
    const int d = tid & 63, ng = tid >> 6;
    #pragma unroll 4
    for (int i = 0; i < 48; ++i) {
        const int n = ny * 192 + i * 4 + ng;
        const unsigned short* wr = woT + (size_t)n * Dd + h * 64;
        float a = 0.f;
        #pragma unroll
        for (int e = 0; e < 64; ++e) a += bf2f(wr[e]) * sKV[d][e];
        W2T[((size_t)b * Dd + n) * Dd + h * 64 + d] = f2bf(a);
    }
}

// ---------------------------------------------------------------------------
extern "C" void kernel_launch(void* const* d_in, const int* in_sizes, int n_in,
                              void* d_out, int out_size, void* d_ws, size_t ws_size,
                              hipStream_t stream) {
    (void)in_sizes; (void)n_in; (void)out_size; (void)ws_size;
    const float* x    = (const float*)d_in[0];
    const float* Wq   = (const float*)d_in[1];
    const float* Wk   = (const float*)d_in[2];
    const float* Wv   = (const float*)d_in[3];
    const float* Wo   = (const float*)d_in[4];
    const float* bo   = (const float*)d_in[5];
    const float* ln1g = (const float*)d_in[6];
    const float* ln1b = (const float*)d_in[7];
    const float* ln2g = (const float*)d_in[8];
    const float* ln2b = (const float*)d_in[9];
    const float* W1   = (const float*)d_in[10];
    const float* b1   = (const float*)d_in[11];
    const float* W2   = (const float*)d_in[12];
    const float* b2   = (const float*)d_in[13];
    float* outp = (float*)d_out;

    char* ws = (char*)d_ws;
    const size_t SZ = Mrows * Dd * 2;                           // bf16 [M][768] slot
    unsigned short* xn = (unsigned short*)(ws + 0);             // s0: LN out
    unsigned short* Qb = (unsigned short*)(ws + SZ);            // s1: Q, later ff1-lo
    unsigned short* Kb = (unsigned short*)(ws + 2 * SZ);        // s2: K, later ff1-hi
    unsigned short* Vb = (unsigned short*)(ws + 3 * SZ);        // s3: V, later x2 bf16
    char* p = ws + 4 * SZ;
    float* part  = (float*)p;  p += (size_t)48 * 8 * 4096 * 4;  // 6.3 MB (later: W2T)
    float* kvf   = (float*)p;  p += (size_t)48 * 4096 * 4;
    float* ksumf = (float*)p;  p += (size_t)48 * 64 * 4;
    unsigned short* wqkvT = (unsigned short*)p; p += (size_t)2304 * 768 * 2;
    unsigned short* woT   = (unsigned short*)p; p += (size_t)768 * 768 * 2;
    unsigned short* w1T   = (unsigned short*)p; p += (size_t)3072 * 768 * 2;
    unsigned short* w2aT  = (unsigned short*)p; p += (size_t)768 * 1536 * 2;
    unsigned short* w2bT  = (unsigned short*)p; p += (size_t)768 * 1536 * 2;
    float* pksum = (float*)p;  p += (size_t)48 * 8 * 64 * 4;
    float* zinv  = (float*)p;  p += (size_t)Mrows * 4;          // 131 KB
    unsigned short* W2T = (unsigned short*)part;   // part dead after kv_reduce
    unsigned short* ff1 = Qb;                      // M x 1536 bf16 = slots s1+s2
    unsigned short* x2b = Vb;

    const dim3 blk(256);
    const dim3 tb(32, 8);

    // 1) all weight transposes in one dispatch
    transpose_all<<<6912, tb, 0, stream>>>(Wq, Wk, Wv, Wo, W1, W2,
                                           wqkvT, woT, w1T, w2aT, w2bT);

    // 2) LN1
    ln_kernel<0><<<32768, blk, 0, stream>>>(x, ln1g, ln1b, xn);

    // 3) fused QKV projection (N=2304): 256 mt x 18 nt = 4608 wg
    gemm97<EPI_QKV, 768, 0><<<4608, blk, 0, stream>>>(xn, wqkvT, nullptr, nullptr, nullptr, Qb, 2304);

    // 4) linear-attention stats: KV and Ksum
    kv_partial<<<dim3(8, 48), blk, 0, stream>>>(Kb, Vb, part, pksum);
    kv_reduce<<<48, blk, 0, stream>>>(part, pksum, kvf, ksumf);

    // 5) zinv[row] = 1/(Q.Ksum + eps); W2 = KV @ Wo (per b,h)
    z_kernel<<<32768, blk, 0, stream>>>(Qb, ksumf, zinv);
    w2_build<<<dim3(48, 4), blk, 0, stream>>>(kvf, woT, W2T);

    // 6) x2 = (Q@W2)*zinv + bo + x : 256 x 6 = 1536 wg, per-batch weights
    gemm97<EPI_X2, 768, 1><<<1536, blk, 0, stream>>>(Qb, W2T, bo, x, zinv, x2b, 768);

    // 7) LN2
    ln_kernel<1><<<32768, blk, 0, stream>>>(x2b, ln2g, ln2b, xn);

    // 8) FFN in two halves (ff1 = M x 1536 bf16 in s1+s2)
    gemm97<EPI_GELU, 768, 0><<<3072, blk, 0, stream>>>(xn, w1T, b1, nullptr, nullptr, ff1, 1536);
    gemm97<EPI_OUT1, 1536, 0><<<1536, blk, 0, stream>>>(ff1, w2aT, b2, x2b, nullptr, outp, 768);
    gemm97<EPI_GELU, 768, 0><<<3072, blk, 0, stream>>>(xn, w1T + (size_t)1536 * 768,
                                                       b1 + 1536, nullptr, nullptr, ff1, 1536);
    gemm97<EPI_OUT2, 1536, 0><<<1536, blk, 0, stream>>>(ff1, w2bT, nullptr, nullptr, nullptr, outp, 768);
}